// Round 2
// baseline (1875.027 us; speedup 1.0000x reference)
//
#include <hip/hip_runtime.h>
#include <hip/hip_cooperative_groups.h>

namespace cg = cooperative_groups;

// ============================================================================
// MYLSTM: functional-basis LSTM, T=49, BATCH=2048, UNITS=DIM=256, QN=9.
//
// Round 2 changes vs round 1:
//  - rec_k launched cooperatively; grid.sync() every 4 steps bounds wg drift
//    so the 128KB UP_t slice stays L2-resident per XCD (round-1 FETCH showed
//    ~1.6GB = every wg re-fetching UP_t from HBM every step).
//  - UP B-frags prefetched into registers at step start (consumed in proj
//    GEMM) -> L2/HBM latency hidden under gate GEMM + elementwise.
//  - out stores back to regular (round-1 nt stores raised WRITE 148->198MB).
//  - __launch_bounds__(1024, 4): VGPR cap 128 (compiler picked 64 in r1).
// ============================================================================

typedef unsigned short u16;
typedef unsigned int u32;
typedef __attribute__((ext_vector_type(8))) short bf16x8;
typedef __attribute__((ext_vector_type(4))) float f32x4;

#define T_STEPS 49
#define OUT_ROW 12544 // 49*256

__device__ __forceinline__ u16 f2b(float f) {
  u32 u = __float_as_uint(f);
  u += 0x7fffu + ((u >> 16) & 1u); // RNE
  return (u16)(u >> 16);
}
__device__ __forceinline__ float b2f(u16 h) { return __uint_as_float(((u32)h) << 16); }
__device__ __forceinline__ float sigm(float z) { return 1.0f / (1.0f + __expf(-z)); }
__device__ __forceinline__ float tanh_f(float z) {
  float e = __expf(-2.0f * fabsf(z));
  float r = (1.0f - e) / (1.0f + e); // overflow-safe: e->0 => 1
  return __builtin_copysignf(r, z);
}

// ---------------------------------------------------------------------------
// Pack weights: WcP[n][k] = W_g[k][u], WxP[n][k] = W_g[256+k][u]; n=g*256+u.
__global__ void pack_w(const float* __restrict__ Wf, const float* __restrict__ Wi,
                       const float* __restrict__ Wc, const float* __restrict__ Wo,
                       u16* __restrict__ WcP, u16* __restrict__ WxP) {
  int n = blockIdx.x, k = threadIdx.x;
  int g = n >> 8, u = n & 255;
  const float* W = (g == 0) ? Wf : (g == 1) ? Wi : (g == 2) ? Wc : Wo;
  WcP[n * 256 + k] = f2b(W[k * 256 + u]);
  WxP[n * 256 + k] = f2b(W[(256 + k) * 256 + u]);
}

// ---------------------------------------------------------------------------
// U pack: UP[t][jp][j] = sum_q Q[j*2304 + jp*9 + q] * B(t,q), bf16.
__global__ void pack_u(const float* __restrict__ Q, u16* __restrict__ UP) {
  int bx = blockIdx.x;
  int t = bx >> 8, jp = bx & 255, j = threadIdx.x;
  const float* q = Q + j * 2304 + jp * 9;
  float tv = (float)t / 48.0f;
  float acc = q[0];
  const float SQ2 = 1.41421356237f;
#pragma unroll
  for (int i = 1; i <= 4; ++i) {
    float ang = 6.283185307179586f * (float)i * tv;
    acc += SQ2 * (sinf(ang) * q[2 * i - 1] + cosf(ang) * q[2 * i]);
  }
  UP[t * 65536 + jp * 256 + j] = f2b(acc);
}

// ---------------------------------------------------------------------------
// xproj: xp[m][n] = x[b, t0+tt, :] @ Wx[:, n], m = b*ct + tt.
// grid (2048*ct/64) wgs x 512 thr. Wave w owns cols w*128..w*128+127.
__global__ __launch_bounds__(512) void xproj_k(const float* __restrict__ x,
                                               const u16* __restrict__ WxP,
                                               u16* __restrict__ xp,
                                               int t0, int ct) {
  __shared__ u16 aLds[64][264]; // +8 pad: breaks 512B-stride bank aliasing
  int tid = threadIdx.x;
  int m0 = blockIdx.x * 64;
  // stage A: 64 rows x 256 k, fp32 -> bf16 (non-temporal: x is read once)
#pragma unroll
  for (int it = 0; it < 8; ++it) {
    int flat = it * 2048 + tid * 4;
    int r = flat >> 8, k = flat & 255;
    int rg = m0 + r;
    int b = rg / ct;
    int tt = rg - b * ct;
    const f32x4 v = __builtin_nontemporal_load(
        (const f32x4*)&x[(b * T_STEPS + (t0 + tt)) * 256 + k]);
    u16 tmp[4] = {f2b(v.x), f2b(v.y), f2b(v.z), f2b(v.w)};
    *(uint2*)&aLds[r][k] = *(uint2*)tmp;
  }
  __syncthreads();
  int w = tid >> 6, l = tid & 63, lane15 = l & 15, quad = l >> 4;
  for (int rtp = 0; rtp < 2; ++rtp) {
    bf16x8 af[2][8];
#pragma unroll
    for (int h = 0; h < 2; ++h)
#pragma unroll
      for (int ks = 0; ks < 8; ++ks)
        af[h][ks] = *(const bf16x8*)&aLds[rtp * 32 + h * 16 + lane15][ks * 32 + quad * 8];
    for (int ctl = 0; ctl < 8; ++ctl) {
      const u16* bp = WxP + (w * 128 + ctl * 16 + lane15) * 256 + quad * 8;
      bf16x8 bf[8];
#pragma unroll
      for (int ks = 0; ks < 8; ++ks) bf[ks] = *(const bf16x8*)(bp + ks * 32);
#pragma unroll
      for (int h = 0; h < 2; ++h) {
        f32x4 acc = {0.f, 0.f, 0.f, 0.f};
#pragma unroll
        for (int ks = 0; ks < 8; ++ks)
          acc = __builtin_amdgcn_mfma_f32_16x16x32_bf16(af[h][ks], bf[ks], acc, 0, 0, 0);
        int col = w * 128 + ctl * 16 + lane15;
        int rloc = rtp * 32 + h * 16 + quad * 4;
#pragma unroll
        for (int i = 0; i < 4; ++i)
          __builtin_nontemporal_store(f2b(acc[i]), &xp[(m0 + rloc + i) * 1024 + col]);
      }
    }
  }
}

// ---------------------------------------------------------------------------
// Recurrent kernel: 256 wgs x 1024 thr (16 waves). wg owns batch rows b0..b0+7.
// Cooperative: grid.sync() every 4 steps keeps wgs near-lockstep so UP_t
// (128KB/step) is fetched once per XCD instead of once per wg.
// Wave w: gate cols w*64..+63 (4 tiles of 16), proj cols w*16..+15 (1 tile).
__global__ __launch_bounds__(1024, 4) void rec_k(const u16* __restrict__ WcP,
                                                 const u16* __restrict__ UP,
                                                 const u16* __restrict__ xp,
                                                 float* __restrict__ out,
                                                 float* __restrict__ cstate,
                                                 int tA, int tB, int cc) {
  cg::grid_group grid = cg::this_grid();
  __shared__ float cF[8][256];   // fp32 cell state
  __shared__ u16 cB[16][264];    // bf16 A-operand (rows 8..15 stay zero)
  __shared__ u16 sB[16][264];
  __shared__ float Z[8][1024];   // gate pre-activations (c-part)
  int tid = threadIdx.x;
  int b0 = blockIdx.x * 8;
  // init LDS
  for (int i = tid; i < 16 * 264; i += 1024) {
    ((u16*)cB)[i] = 0;
    ((u16*)sB)[i] = 0;
  }
  for (int i = tid; i < 2048; i += 1024) {
    int r = i >> 8, u = i & 255;
    float c0 = (tA == 0) ? 0.0f : cstate[(b0 + r) * 256 + u];
    cF[r][u] = c0;
    cB[r][u] = f2b(c0);
  }
  __syncthreads();
  int w = tid >> 6, l = tid & 63, lane15 = l & 15, quad = l >> 4;

#pragma unroll 1
  for (int t = tA; t < tB; ++t) {
    // prefetch xproj for the elementwise phase (hidden under gate GEMM).
    // nt: xp is a one-shot 205MB stream; keep it out of L2 so WcP/UP_t stay.
    u16 xpv[2][4];
#pragma unroll
    for (int p = 0; p < 2; ++p) {
      int idx = tid + p * 1024;
      int r = idx >> 8, u = idx & 255;
      const u16* xb = xp + ((b0 + r) * cc + (t - tA)) * 1024 + u;
#pragma unroll
      for (int g = 0; g < 4; ++g) xpv[p][g] = __builtin_nontemporal_load(xb + g * 256);
    }
    // prefetch this step's UP B-frags into regs (consumed in proj GEMM);
    // L2 latency hides under gate GEMM + elementwise. Regular loads: UP_t is
    // SHARED across all wgs on the XCD — we want it cached.
    bf16x8 upf[8];
    {
      const u16* up = UP + t * 65536 + (w * 16 + lane15) * 256 + quad * 8;
#pragma unroll
      for (int ks = 0; ks < 8; ++ks) upf[ks] = *(const bf16x8*)(up + ks * 32);
    }
    // ---- gate GEMM: wave w covers cols w*64 .. +63 (4 tiles of 16)
    bf16x8 af[8];
#pragma unroll
    for (int ks = 0; ks < 8; ++ks)
      af[ks] = *(const bf16x8*)&cB[lane15][ks * 32 + quad * 8];
#pragma unroll
    for (int c8 = 0; c8 < 4; ++c8) {
      f32x4 acc = {0.f, 0.f, 0.f, 0.f};
      const u16* bp = WcP + (w * 64 + c8 * 16 + lane15) * 256 + quad * 8;
#pragma unroll
      for (int ks = 0; ks < 8; ++ks)
        acc = __builtin_amdgcn_mfma_f32_16x16x32_bf16(af[ks], *(const bf16x8*)(bp + ks * 32), acc, 0, 0, 0);
      if (quad < 2) {
        int col = w * 64 + c8 * 16 + lane15;
#pragma unroll
        for (int i = 0; i < 4; ++i) Z[quad * 4 + i][col] = acc[i];
      }
    }
    __syncthreads();
    // ---- elementwise (fp32)
#pragma unroll
    for (int p = 0; p < 2; ++p) {
      int idx = tid + p * 1024;
      int r = idx >> 8, u = idx & 255;
      float zf = Z[r][u] + b2f(xpv[p][0]);
      float zi = Z[r][256 + u] + b2f(xpv[p][1]);
      float zg = Z[r][512 + u] + b2f(xpv[p][2]);
      float zo = Z[r][768 + u] + b2f(xpv[p][3]);
      float f = sigm(zf), ii = sigm(zi), gg = sigm(zg), o = tanh_f(zo);
      float cn = ii * gg + f * cF[r][u];
      cF[r][u] = cn;
      cB[r][u] = f2b(cn);
      float s = o * tanh_f(cn);
      sB[r][u] = f2b(s);
    }
    __syncthreads();
    // ---- proj GEMM: wave w covers cols w*16 .. +15 (1 tile), B from upf regs
    bf16x8 sf[8];
#pragma unroll
    for (int ks = 0; ks < 8; ++ks)
      sf[ks] = *(const bf16x8*)&sB[lane15][ks * 32 + quad * 8];
    {
      f32x4 acc = {0.f, 0.f, 0.f, 0.f};
#pragma unroll
      for (int ks = 0; ks < 8; ++ks)
        acc = __builtin_amdgcn_mfma_f32_16x16x32_bf16(sf[ks], upf[ks], acc, 0, 0, 0);
      if (quad < 2) {
        int col = w * 16 + lane15;
#pragma unroll
        for (int i = 0; i < 4; ++i)
          out[(b0 + quad * 4 + i) * OUT_ROW + t * 256 + col] = tanh_f(acc[i]);
      }
    }
    // keep all wgs near-lockstep so UP_t is shared in L2 across the XCD
    if (((t - tA) & 3) == 3 && (t + 1) < tB) grid.sync();
    // no wg barrier needed otherwise: next gate GEMM's Z writes / cB reads are
    // fenced by this step's two barriers.
  }
  if (tB < T_STEPS) {
    for (int i = tid; i < 2048; i += 1024) {
      int r = i >> 8, u = i & 255;
      cstate[(b0 + r) * 256 + u] = cF[r][u];
    }
  }
}

// ---------------------------------------------------------------------------
extern "C" void kernel_launch(void* const* d_in, const int* in_sizes, int n_in,
                              void* d_out, int out_size, void* d_ws, size_t ws_size,
                              hipStream_t stream) {
  const float* x = (const float*)d_in[0];
  const float* Wf = (const float*)d_in[1];
  const float* Wi = (const float*)d_in[2];
  const float* Wc = (const float*)d_in[3];
  const float* Wo = (const float*)d_in[4];
  const float* Q = (const float*)d_in[5];
  float* out = (float*)d_out;

  char* p = (char*)d_ws;
  u16* WcP = (u16*)p;           p += (size_t)1024 * 256 * 2;        // 512 KB
  u16* WxP = (u16*)p;           p += (size_t)1024 * 256 * 2;        // 512 KB
  u16* UP = (u16*)p;            p += (size_t)49 * 256 * 256 * 2;    // 6.13 MB
  float* cstate = (float*)p;    p += (size_t)2048 * 256 * 4;        // 2 MB
  u16* xpb = (u16*)p;
  size_t used = (size_t)(p - (char*)d_ws);
  size_t rem = (ws_size > used) ? (ws_size - used) : 0;
  const size_t perT = (size_t)2048 * 1024 * 2; // 4 MB per timestep of xproj
  int CT = (int)(rem / perT);
  if (CT > 49) CT = 49;
  if (CT < 1) CT = 1; // require ~14 MB of ws minimum

  pack_w<<<dim3(1024), dim3(256), 0, stream>>>(Wf, Wi, Wc, Wo, WcP, WxP);
  pack_u<<<dim3(49 * 256), dim3(256), 0, stream>>>(Q, UP);

  for (int t0 = 0; t0 < T_STEPS; t0 += CT) {
    int cc = (T_STEPS - t0 < CT) ? (T_STEPS - t0) : CT;
    xproj_k<<<dim3(2048 * cc / 64), dim3(512), 0, stream>>>(x, WxP, xpb, t0, cc);
    int tBv = t0 + cc;
    void* kargs[] = {(void*)&WcP, (void*)&UP, (void*)&xpb, (void*)&out,
                     (void*)&cstate, (void*)&t0, (void*)&tBv, (void*)&cc};
    hipLaunchCooperativeKernel((const void*)rec_k, dim3(256), dim3(1024), kargs,
                               0, stream);
  }
}

// Round 4
// 1510.180 us; speedup vs baseline: 1.2416x; 1.2416x over previous
//
#include <hip/hip_runtime.h>

// ============================================================================
// MYLSTM: functional-basis LSTM, T=49, BATCH=2048, UNITS=DIM=256, QN=9.
//
// Round 4 == round 3 resubmit (round-3 bench died in container acquire, no
// counters; source re-audited: bounds, races, fragment layouts all check out).
//
// Structure:
//  - KEY: h is NOT recurrent (only c is). Proj GEMM h=tanh(s@U_t) moved OUT of
//    the serial loop: rec_k stores s (bf16) to workspace; proj_k does 49
//    batched M=2048 GEMMs afterwards. All UP traffic leaves the serial path.
//  - Gate GEMM fused to K=512: A=[c|x_t], B=[Wc;Wx] (WP, n-major, n=g*256+u).
//    xproj_k deleted; xp HBM round-trip (410MB) deleted; x read once (nt).
//  - Gate-per-lane layout: wave w computes cols {g*256+w*16+lane15, g=0..3} ->
//    each lane holds all 4 gates for its (rows quad*4..+3, unit u_own) in
//    REGISTERS. No Z LDS, no elementwise barrier, c-state in 4 VGPRs.
//  - 128 wgs x 1024 thr; wg owns 16 batch rows (full M-tile). A in LDS,
//    double-buffered, XOR-swizzled (byte ^= (row&7)<<4): one barrier/step.
//  - No cooperative launch, no grid.sync, no register prefetch across barriers.
// ============================================================================

typedef unsigned short u16;
typedef unsigned int u32;
typedef __attribute__((ext_vector_type(8))) short bf16x8;
typedef __attribute__((ext_vector_type(4))) float f32x4;

#define T_STEPS 49
#define OUT_ROW 12544 // 49*256

__device__ __forceinline__ u16 f2b(float f) {
  u32 u = __float_as_uint(f);
  u += 0x7fffu + ((u >> 16) & 1u); // RNE
  return (u16)(u >> 16);
}
__device__ __forceinline__ float b2f(u16 h) { return __uint_as_float(((u32)h) << 16); }
__device__ __forceinline__ float sigm(float z) { return 1.0f / (1.0f + __expf(-z)); }
__device__ __forceinline__ float tanh_f(float z) {
  float e = __expf(-2.0f * fabsf(z));
  float r = (1.0f - e) / (1.0f + e); // overflow-safe: e->0 => 1
  return __builtin_copysignf(r, z);
}

// ---------------------------------------------------------------------------
// Pack fused weights: WP[n][k], n=g*256+u (g in {f,i,c,o}), k=0..511 over
// cat=[c|x]. WP[n*512+k] = W_g[k][u].
__global__ void pack_w(const float* __restrict__ Wf, const float* __restrict__ Wi,
                       const float* __restrict__ Wc, const float* __restrict__ Wo,
                       u16* __restrict__ WP) {
  int n = blockIdx.x, k = threadIdx.x;
  int g = n >> 8, u = n & 255;
  const float* W = (g == 0) ? Wf : (g == 1) ? Wi : (g == 2) ? Wc : Wo;
  WP[n * 512 + k] = f2b(W[k * 256 + u]);
  WP[n * 512 + 256 + k] = f2b(W[(256 + k) * 256 + u]);
}

// ---------------------------------------------------------------------------
// U pack: UP[t][jp][j] = sum_q Q[j*2304 + jp*9 + q] * B(t,q), bf16.
// (B-operand for proj: col jp, k j, k-contiguous.)
__global__ void pack_u(const float* __restrict__ Q, u16* __restrict__ UP) {
  int bx = blockIdx.x;
  int t = bx >> 8, jp = bx & 255, j = threadIdx.x;
  const float* q = Q + j * 2304 + jp * 9;
  float tv = (float)t / 48.0f;
  float acc = q[0];
  const float SQ2 = 1.41421356237f;
#pragma unroll
  for (int i = 1; i <= 4; ++i) {
    float ang = 6.283185307179586f * (float)i * tv;
    acc += SQ2 * (sinf(ang) * q[2 * i - 1] + cosf(ang) * q[2 * i]);
  }
  UP[t * 65536 + jp * 256 + j] = f2b(acc);
}

// ---------------------------------------------------------------------------
// Recurrent kernel: 128 wgs x 1024 thr (16 waves). wg owns batch rows b0..b0+15.
// Per step: Z[16][1024] = [c|x_t] @ WP (K=512), elementwise in-register,
// cn -> next A-buf (LDS), s -> S (global, bf16). One barrier per step.
__global__ __launch_bounds__(1024) void rec_k(const u16* __restrict__ WP,
                                              const float* __restrict__ x,
                                              u16* __restrict__ S) {
  __shared__ u16 aB[2][16 * 512]; // 2 x 16KB, byte col ^= (row&7)<<4 swizzle
  int tid = threadIdx.x;
  int b0 = blockIdx.x * 16;
  int w = tid >> 6, l = tid & 63, lane15 = l & 15, quad = l >> 4;
  int u_own = w * 16 + lane15; // this lane's unit (all 4 gates, 4 rows)

  int sr = tid >> 6;        // staging row (one per wave)
  int sc = (tid & 63) * 4;  // staging col, 4 floats per lane

  // prologue: zero c-part of aB[0], stage x(t=0) into x-part of aB[0]
  {
    uint2 z2 = {0u, 0u};
    int bc = sc * 2; // c-part byte col (8B aligned; XOR bits 4-6 keep it in-slot)
    *(uint2*)((char*)&aB[0][0] + sr * 1024 + (bc ^ ((sr & 7) << 4))) = z2;
    const f32x4 v = __builtin_nontemporal_load(
        (const f32x4*)&x[((size_t)(b0 + sr) * T_STEPS + 0) * 256 + sc]);
    u16 tmp[4] = {f2b(v.x), f2b(v.y), f2b(v.z), f2b(v.w)};
    int bx2 = 512 + sc * 2; // x-part byte col
    *(uint2*)((char*)&aB[0][0] + sr * 1024 + (bx2 ^ ((sr & 7) << 4))) = *(uint2*)tmp;
  }
  __syncthreads();

  float creg[4] = {0.f, 0.f, 0.f, 0.f};
  // B pointers: one per gate; frag k-offset quad*8, tile col = lane15
  const u16* bp0 = WP + ((size_t)(0 * 256 + u_own)) * 512 + quad * 8;
  const u16* bp1 = WP + ((size_t)(1 * 256 + u_own)) * 512 + quad * 8;
  const u16* bp2 = WP + ((size_t)(2 * 256 + u_own)) * 512 + quad * 8;
  const u16* bp3 = WP + ((size_t)(3 * 256 + u_own)) * 512 + quad * 8;
  u16* Sl = S + (size_t)(b0 + quad * 4) * 256 + u_own;

  int p = 0;
#pragma unroll 1
  for (int t = 0; t < T_STEPS; ++t) {
    // issue next-step x load early (hides HBM latency under gate GEMM)
    f32x4 xv = {0.f, 0.f, 0.f, 0.f};
    if (t + 1 < T_STEPS)
      xv = __builtin_nontemporal_load(
          (const f32x4*)&x[((size_t)(b0 + sr) * T_STEPS + (t + 1)) * 256 + sc]);

    // ---- gate GEMM: 4 gate tiles, K=512 (16 k-chunks of 32)
    f32x4 a0 = {0.f, 0.f, 0.f, 0.f}, a1 = a0, a2 = a0, a3 = a0;
    const char* ab = (const char*)&aB[p][0];
#pragma unroll
    for (int ks = 0; ks < 16; ++ks) {
      bf16x8 af = *(const bf16x8*)(ab + lane15 * 1024 +
                                   ((ks * 64 + quad * 16) ^ ((lane15 & 7) << 4)));
      a0 = __builtin_amdgcn_mfma_f32_16x16x32_bf16(af, *(const bf16x8*)(bp0 + ks * 32), a0, 0, 0, 0);
      a1 = __builtin_amdgcn_mfma_f32_16x16x32_bf16(af, *(const bf16x8*)(bp1 + ks * 32), a1, 0, 0, 0);
      a2 = __builtin_amdgcn_mfma_f32_16x16x32_bf16(af, *(const bf16x8*)(bp2 + ks * 32), a2, 0, 0, 0);
      a3 = __builtin_amdgcn_mfma_f32_16x16x32_bf16(af, *(const bf16x8*)(bp3 + ks * 32), a3, 0, 0, 0);
    }

    // ---- elementwise, fully in-register (lane owns rows quad*4..+3, unit u_own)
    char* abn = (char*)&aB[p ^ 1][0];
#pragma unroll
    for (int i = 0; i < 4; ++i) {
      int r = quad * 4 + i;
      float f = sigm(a0[i]), ii = sigm(a1[i]), gg = sigm(a2[i]), o = tanh_f(a3[i]);
      float cn = ii * gg + f * creg[i];
      creg[i] = cn;
      if (t + 1 < T_STEPS)
        *(u16*)(abn + r * 1024 + ((u_own * 2) ^ ((r & 7) << 4))) = f2b(cn);
      float s = o * tanh_f(cn);
      Sl[((size_t)t * 2048 + i) * 256] = f2b(s);
    }

    // ---- write staged x_{t+1} into next A-buf
    if (t + 1 < T_STEPS) {
      u16 tmp[4] = {f2b(xv.x), f2b(xv.y), f2b(xv.z), f2b(xv.w)};
      int bx2 = 512 + sc * 2;
      *(uint2*)(abn + sr * 1024 + (bx2 ^ ((sr & 7) << 4))) = *(uint2*)tmp;
    }
    __syncthreads();
    p ^= 1;
  }
}

// ---------------------------------------------------------------------------
// Proj kernel: h = tanh(S_t @ U_t), per t: M=2048, N=256, K=256.
// grid 49*32 wgs x 512 thr (8 waves); bx -> (t, mtile of 64 rows).
// t-major block order => 32 consecutive wgs share UP_t via L2.
__global__ __launch_bounds__(512) void proj_k(const u16* __restrict__ S,
                                              const u16* __restrict__ UP,
                                              float* __restrict__ out) {
  int bx = blockIdx.x;
  int t = bx >> 5, mt = bx & 31;
  int m0 = mt * 64;
  int tid = threadIdx.x;
  int w = tid >> 6, l = tid & 63, lane15 = l & 15, quad = l >> 4;
  const u16* Sbase = S + ((size_t)t * 2048 + m0) * 256;
  const u16* Ubase = UP + (size_t)t * 65536;
#pragma unroll
  for (int rtp = 0; rtp < 2; ++rtp) {
    bf16x8 af[2][8];
#pragma unroll
    for (int h = 0; h < 2; ++h)
#pragma unroll
      for (int ks = 0; ks < 8; ++ks)
        af[h][ks] = *(const bf16x8*)(Sbase + (rtp * 32 + h * 16 + lane15) * 256 +
                                     ks * 32 + quad * 8);
#pragma unroll
    for (int ct = 0; ct < 2; ++ct) {
      int col = w * 32 + ct * 16 + lane15;
      const u16* up = Ubase + col * 256 + quad * 8;
      bf16x8 bf[8];
#pragma unroll
      for (int ks = 0; ks < 8; ++ks) bf[ks] = *(const bf16x8*)(up + ks * 32);
#pragma unroll
      for (int h = 0; h < 2; ++h) {
        f32x4 acc = {0.f, 0.f, 0.f, 0.f};
#pragma unroll
        for (int ks = 0; ks < 8; ++ks)
          acc = __builtin_amdgcn_mfma_f32_16x16x32_bf16(af[h][ks], bf[ks], acc, 0, 0, 0);
#pragma unroll
        for (int i = 0; i < 4; ++i) {
          int b = m0 + rtp * 32 + h * 16 + quad * 4 + i;
          out[(size_t)b * OUT_ROW + t * 256 + col] = tanh_f(acc[i]);
        }
      }
    }
  }
}

// ---------------------------------------------------------------------------
extern "C" void kernel_launch(void* const* d_in, const int* in_sizes, int n_in,
                              void* d_out, int out_size, void* d_ws, size_t ws_size,
                              hipStream_t stream) {
  const float* x = (const float*)d_in[0];
  const float* Wf = (const float*)d_in[1];
  const float* Wi = (const float*)d_in[2];
  const float* Wc = (const float*)d_in[3];
  const float* Wo = (const float*)d_in[4];
  const float* Q = (const float*)d_in[5];
  float* out = (float*)d_out;

  char* p = (char*)d_ws;
  u16* WP = (u16*)p;  p += (size_t)1024 * 512 * 2;        // 1 MB fused gate weights
  u16* UP = (u16*)p;  p += (size_t)49 * 256 * 256 * 2;    // 6.13 MB
  u16* Sb = (u16*)p;  p += (size_t)49 * 2048 * 256 * 2;   // 51.4 MB s-values
  (void)ws_size;

  pack_w<<<dim3(1024), dim3(256), 0, stream>>>(Wf, Wi, Wc, Wo, WP);
  pack_u<<<dim3(49 * 256), dim3(256), 0, stream>>>(Q, UP);
  rec_k<<<dim3(128), dim3(1024), 0, stream>>>(WP, x, Sb);
  proj_k<<<dim3(49 * 32), dim3(512), 0, stream>>>(Sb, UP, out);
}